// Round 4
// baseline (96.771 us; speedup 1.0000x reference)
//
#include <hip/hip_runtime.h>
#include <hip/hip_bf16.h>
#include <math.h>

// Problem constants (B=16, T=3000, F=201)
constexpr int BB     = 16;
constexpr int T      = 3000;
constexpr int F      = 201;
constexpr int NFFT   = 400;
constexpr int HOP    = 160;
constexpr int K      = 402;            // 2*F real/imag interleaved
constexpr int ESTLEN = (T - 1) * HOP + NFFT;   // 480240
constexpr int OUTLEN = ESTLEN - NFFT;          // 479840 per batch
constexpr float EPS  = 1e-12f;

constexpr int UT    = 192;             // u-rows per block (4 u-waves x 48)
constexpr int AR    = 194;             // A rows per step tile (halo 2)
constexpr int NSTEP = 13;              // k-steps of 32 (step 0 = k 384..415)
constexpr int WJ    = 480;             // W rows: j = m + 160*dt
constexpr int WS_SH = WJ * 32;         // shorts per W LDS buffer (30720 B)
constexpr int AS_FL = AR * 32;         // floats per A LDS buffer (24832 B)

typedef short bf16x8 __attribute__((ext_vector_type(8)));
typedef float f32x4  __attribute__((ext_vector_type(4)));

__device__ __forceinline__ unsigned short f2bf(float f) {
    unsigned int u = __float_as_uint(f);
    u = (u + 0x7fffu + ((u >> 16) & 1u)) >> 16;
    return (unsigned short)u;
}

__device__ __forceinline__ bf16x8 cvt8(float4 a, float4 b) {
    __hip_bfloat162 h0 = __float22bfloat162_rn(make_float2(a.x, a.y));
    __hip_bfloat162 h1 = __float22bfloat162_rn(make_float2(a.z, a.w));
    __hip_bfloat162 h2 = __float22bfloat162_rn(make_float2(b.x, b.y));
    __hip_bfloat162 h3 = __float22bfloat162_rn(make_float2(b.z, b.w));
    union U { bf16x8 v; __hip_bfloat162 h[4]; } u;
    u.h[0] = h0; u.h[1] = h1; u.h[2] = h2; u.h[3] = h3;
    return u.v;
}

// ---------------- table builders ----------------

// Wg: per-k-step fragment-linear W. Layout: [ksg 0..12][j 0..479][kk 0..31],
// element = W[k = ksg*32 + kk][j], zero if j>=400 or k>=402.
__global__ void build_wt(unsigned short* __restrict__ Wg) {
    int idx = blockIdx.x * blockDim.x + threadIdx.x;
    if (idx >= NSTEP * WJ * 32) return;
    int ksg = idx / (WJ * 32);
    int rem = idx - ksg * (WJ * 32);
    int j  = rem >> 5;
    int kk = rem & 31;
    int k  = ksg * 32 + kk;
    float v = 0.f;
    if (j < NFFT && k < K) {
        int f = k >> 1;
        bool is_re = (k & 1) == 0;
        float c = (f == 0 || f == F - 1) ? (1.f / 400.f) : (2.f / 400.f);
        int m = (j * f) % NFFT;
        float ang = (float)(2.0 * M_PI * (double)m / 400.0);
        float tw = is_re ? cosf(ang) : -sinf(ang);
        float win = 0.54f - 0.46f * cosf((float)(2.0 * M_PI * (double)j / 400.0));
        v = c * tw * win;
    }
    Wg[idx] = f2bf(v);
}

__global__ void build_rssw(float* __restrict__ rssw) {
    int p = blockIdx.x * blockDim.x + threadIdx.x;
    if (p >= ESTLEN) return;
    int t_hi = p / HOP; if (t_hi > T - 1) t_hi = T - 1;
    int t_lo = (p >= NFFT) ? ((p - NFFT) / HOP + 1) : 0;
    float s = 0.f;
    for (int t = t_lo; t <= t_hi; ++t) {
        int j = p - t * HOP;
        float w = 0.54f - 0.46f * cosf((float)(2.0 * M_PI * (double)j / 400.0));
        s += w * w;
    }
    rssw[p] = (s > EPS) ? 1.f / s : 1.f;
}

// ---------------- fused MFMA gather-GEMM ----------------
// Block: 512 thr = 8 waves (4u x 2m). Block tile 192u x 160m. 1 block/CU.
// Wave: 48u x 80m = Mt3 x Nm5 frags of 16x16. K: 13 steps of 32.
__global__ __launch_bounds__(512)
void istft_fused(const float* __restrict__ A, const unsigned short* __restrict__ Wg,
                 const float* __restrict__ rssw, const float* __restrict__ zpage,
                 float* __restrict__ out) {
    __shared__ unsigned short Ws[2 * WS_SH];           // 61440 B
    __shared__ float As[2 * AS_FL + 16];               // 49792 B

    const int tid  = threadIdx.x;
    const int lane = tid & 63;
    const int w    = tid >> 6;
    const int wu   = w >> 1;           // 0..3
    const int wm   = w & 1;            // 0..1
    const int l15  = lane & 15;
    const int kg   = lane >> 4;        // 0..3
    const int b    = blockIdx.y;
    const int u0   = 1 + blockIdx.x * UT;
    const int tbase = u0 - 2;

    f32x4 acc[3][5];
    #pragma unroll
    for (int i = 0; i < 3; ++i)
        #pragma unroll
        for (int mf = 0; mf < 5; ++mf)
            #pragma unroll
            for (int q = 0; q < 4; ++q) acc[i][mf][q] = 0.f;

    // ---- precomputed per-thread source pointers (loop-invariant) ----
    // A: dword-granular. P = p*512+tid; row r=P>>5, phys dword pd=P&31,
    // logical dword ld = pd ^ ((r&6)<<2); src row pointer folded w/ zpage.
    const float* a_src[13];
    #pragma unroll
    for (int p = 0; p < 13; ++p) {
        int P  = p * 512 + tid;
        int r  = P >> 5;
        int pd = P & 31;
        int ld = pd ^ ((r & 6) << 2);
        int t  = tbase + r;
        bool v = (P < AR * 32) && (t >= 0 && t < T);
        // zpage has 512 zero floats, so +k0 (<=384) +ld stays in-bounds
        a_src[p] = v ? (A + (size_t)(b * T + t) * K + ld) : (zpage + ld);
    }
    const unsigned short* w_src[4];
    #pragma unroll
    for (int p = 0; p < 4; ++p) w_src[p] = Wg + (size_t)(p * 512 + tid) * 8;

    auto issue_W = [&](int buf, int ksg) {
        unsigned short* dstb = &Ws[buf * WS_SH];
        #pragma unroll
        for (int p = 0; p < 4; ++p) {
            int P = p * 512 + tid;
            if (P < WJ * 4) {                      // wave-uniform (384 = 6 waves)
                __builtin_amdgcn_global_load_lds(
                    (const __attribute__((address_space(1))) void*)(w_src[p] + (size_t)ksg * WS_SH),
                    (__attribute__((address_space(3))) void*)(dstb + (p * 512 + w * 64) * 8),
                    16, 0, 0);
            }
        }
    };

    auto issue_A = [&](int buf, int k0) {
        float* dstb = &As[buf * AS_FL];
        #pragma unroll
        for (int p = 0; p < 13; ++p) {
            int P = p * 512 + tid;
            if (P < AR * 32) {                     // wave-uniform (6208 = 97 waves)
                __builtin_amdgcn_global_load_lds(
                    (const __attribute__((address_space(1))) void*)(a_src[p] + k0),
                    (__attribute__((address_space(3))) void*)(dstb + p * 512 + w * 64),
                    4, 0, 0);
            }
        }
    };

    // special prologue stage for k0=384 (guarded: k>=402 zero, row-end safety)
    auto stage_A0 = [&]() {
        #pragma unroll
        for (int p = 0; p < 4; ++p) {
            int C = p * 512 + tid;                 // 16B chunk index
            if (C < AR * 8) {
                int r  = C >> 3;
                int cp = C & 7;
                int cl = cp ^ (r & 6);
                int k  = 384 + cl * 4;
                int t  = tbase + r;
                float4 v = make_float4(0.f, 0.f, 0.f, 0.f);
                if (t >= 0 && t < T) {
                    const float* sr = A + (size_t)(b * T + t) * K;
                    v.x = (k + 0 < K) ? sr[k + 0] : 0.f;
                    v.y = (k + 1 < K) ? sr[k + 1] : 0.f;
                    v.z = (k + 2 < K) ? sr[k + 2] : 0.f;
                    v.w = (k + 3 < K) ? sr[k + 3] : 0.f;
                }
                *reinterpret_cast<float4*>(&As[C * 4]) = v;
            }
        }
    };

    auto compute = [&](int buf) {
        const float* Ab = &As[buf * AS_FL];
        const unsigned short* Wb = &Ws[buf * WS_SH];
        bf16x8 af[3][3];
        #pragma unroll
        for (int i = 0; i < 3; ++i)
            #pragma unroll
            for (int dt = 0; dt < 3; ++dt) {
                int r  = wu * 48 + 16 * i + l15 + (2 - dt);
                int s0 = (2 * kg) ^ (r & 6);       // even (r&6 even) -> s1 = s0+1
                float4 lo = *reinterpret_cast<const float4*>(&Ab[r * 32 + s0 * 4]);
                float4 hi = *reinterpret_cast<const float4*>(&Ab[r * 32 + (s0 ^ 1) * 4]);
                af[i][dt] = cvt8(lo, hi);
            }
        #pragma unroll
        for (int dt = 0; dt < 3; ++dt) {
            bf16x8 bf[5];
            #pragma unroll
            for (int mf = 0; mf < 5; ++mf) {
                int j = dt * 160 + wm * 80 + mf * 16 + l15;
                bf[mf] = *reinterpret_cast<const bf16x8*>(&Wb[j * 32 + kg * 8]);
            }
            #pragma unroll
            for (int i = 0; i < 3; ++i)
                #pragma unroll
                for (int mf = 0; mf < 5; ++mf)
                    acc[i][mf] = __builtin_amdgcn_mfma_f32_16x16x32_bf16(
                        af[i][dt], bf[mf], acc[i][mf], 0, 0, 0);
        }
    };

    // ---- prologue: step 0 = k0 384 (special A) + W ksg=12 ----
    stage_A0();
    issue_W(0, 12);
    __syncthreads();

    // ---- main loop: issue(s+1) -> compute(s) -> barrier ----
    for (int s = 0; s < NSTEP; ++s) {
        if (s + 1 < NSTEP) {
            issue_W((s + 1) & 1, s);       // step s+1 covers k0 = s*32
            issue_A((s + 1) & 1, s * 32);
        }
        compute(s & 1);
        __syncthreads();
    }

    // ---- epilogue: each output owned by exactly one block; no memset needed ----
    #pragma unroll
    for (int i = 0; i < 3; ++i)
        #pragma unroll
        for (int mf = 0; mf < 5; ++mf)
            #pragma unroll
            for (int q = 0; q < 4; ++q) {
                int u  = u0 + wu * 48 + 16 * i + kg * 4 + q;
                int m  = wm * 80 + mf * 16 + l15;
                int pe = u * HOP + m;
                int po = pe - (NFFT / 2);
                if (po >= 0 && po < OUTLEN)
                    out[(size_t)b * OUTLEN + po] = acc[i][mf][q] * rssw[pe];
            }
}

// ---------------- launcher ----------------
extern "C" void kernel_launch(void* const* d_in, const int* in_sizes, int n_in,
                              void* d_out, int out_size, void* d_ws, size_t ws_size,
                              hipStream_t stream) {
    const float* x = (const float*)d_in[0];
    float* out = (float*)d_out;

    char* ws = (char*)d_ws;
    unsigned short* Wg = (unsigned short*)ws;                    // 399,360 B
    float* rssw = (float*)(ws + 399360);                         // 1,920,960 B
    float* zpage = (float*)(ws + 399360 + 1920960);              // 2048 B zeros

    hipMemsetAsync(zpage, 0, 2048, stream);
    {
        int total = NSTEP * WJ * 32;
        build_wt<<<(total + 255) / 256, 256, 0, stream>>>(Wg);
    }
    {
        build_rssw<<<(ESTLEN + 255) / 256, 256, 0, stream>>>(rssw);
    }
    {
        dim3 grid(16, BB);                                       // 256 blocks = 1/CU
        istft_fused<<<grid, 512, 0, stream>>>(x, Wg, rssw, zpage, out);
    }
}

// Round 5
// 77.129 us; speedup vs baseline: 1.2547x; 1.2547x over previous
//
#include <hip/hip_runtime.h>
#include <hip/hip_bf16.h>
#include <math.h>

// Problem constants (B=16, T=3000, F=201)
constexpr int BB     = 16;
constexpr int T      = 3000;
constexpr int F      = 201;
constexpr int NFFT   = 400;
constexpr int HOP    = 160;
constexpr int K      = 402;            // 2*F real/imag interleaved
constexpr int ESTLEN = (T - 1) * HOP + NFFT;   // 480240
constexpr int OUTLEN = ESTLEN - NFFT;          // 479840 per batch
constexpr float EPS  = 1e-12f;

constexpr int WJ    = 416;             // W rows per step (j 0..415; 400+ zero)
constexpr int WSTEP = WJ * 32;         // shorts per k32 table step = 13312
constexpr int NSTEP = 13;              // k-steps of 32 (step 12 = tail 384..401)
constexpr int UT    = 64;              // u-rows per block (2 wu x 32)

typedef short bf16x8 __attribute__((ext_vector_type(8)));
typedef float f32x16 __attribute__((ext_vector_type(16)));

__device__ __forceinline__ unsigned short f2bf(float f) {
    unsigned int u = __float_as_uint(f);
    u = (u + 0x7fffu + ((u >> 16) & 1u)) >> 16;
    return (unsigned short)u;
}

// ---------------- table builders ----------------
// Wg[ksg][P=j*4+sp][w]: bank-swizzle baked: logical slot s = sp ^ (j&3),
// k = ksg*32 + s*8 + w  (normal), tail ksg=12: s<2 same; s==2 -> k=394+w
// (zeroed for w<6 to avoid double-count); s==3 -> zero.
__global__ void build_wt(unsigned short* __restrict__ Wg) {
    int idx = blockIdx.x * blockDim.x + threadIdx.x;
    if (idx >= NSTEP * WSTEP) return;
    int ksg = idx / WSTEP;
    int rem = idx - ksg * WSTEP;
    int j  = rem >> 5;
    int kk = rem & 31;
    int sp = kk >> 3;
    int ww = kk & 7;
    int s  = sp ^ (j & 3);
    float v = 0.f;
    if (j < NFFT) {
        int k = -1;
        if (ksg == 12 && s >= 2) {
            if (s == 2 && ww >= 6) k = 394 + ww;   // 400, 401
        } else {
            k = ksg * 32 + s * 8 + ww;
        }
        if (k >= 0 && k < K) {
            int f = k >> 1;
            bool is_re = (k & 1) == 0;
            float c = (f == 0 || f == F - 1) ? (1.f / 400.f) : (2.f / 400.f);
            int m = (j * f) % NFFT;
            float ang = (float)(2.0 * M_PI * (double)m / 400.0);
            float tw = is_re ? cosf(ang) : -sinf(ang);
            float win = 0.54f - 0.46f * cosf((float)(2.0 * M_PI * (double)j / 400.0));
            v = c * tw * win;
        }
    }
    Wg[idx] = f2bf(v);
}

__global__ void build_rssw(float* __restrict__ rssw) {
    int p = blockIdx.x * blockDim.x + threadIdx.x;
    if (p >= ESTLEN) return;
    int t_hi = p / HOP; if (t_hi > T - 1) t_hi = T - 1;
    int t_lo = (p >= NFFT) ? ((p - NFFT) / HOP + 1) : 0;
    float s = 0.f;
    for (int t = t_lo; t <= t_hi; ++t) {
        int j = p - t * HOP;
        float w = 0.54f - 0.46f * cosf((float)(2.0 * M_PI * (double)j / 400.0));
        s += w * w;
    }
    rssw[p] = (s > EPS) ? 1.f / s : 1.f;
}

// ---------------- fused MFMA gather-GEMM ----------------
// Block 256 thr = 4 waves: (wu 0..1) x (kh 0..1). Tile 64u x 160m.
// Wave: 32u x 160m, k-half kh. 32x32x16 MFMA, acc 5 frags. K: 13 steps of 32.
__global__ __launch_bounds__(256, 3)
void istft_fused(const float* __restrict__ A, const unsigned short* __restrict__ Wg,
                 const float* __restrict__ rssw, const float* __restrict__ zpage,
                 float* __restrict__ out) {
    __shared__ unsigned short Ws[2 * WSTEP];          // 53,248 B

    const int tid  = threadIdx.x;
    const int lane = tid & 63;
    const int w    = tid >> 6;
    const int kh   = w >> 1;           // k-half 0/1
    const int wu   = w & 1;            // u-band 0/1
    const int lj   = lane & 31;        // A row / B col within frag
    const int lh   = lane >> 5;        // k-octet select
    const int b    = blockIdx.y;
    const int u0   = 1 + blockIdx.x * UT;

    f32x16 acc[5];
    #pragma unroll
    for (int mf = 0; mf < 5; ++mf)
        #pragma unroll
        for (int q = 0; q < 16; ++q) acc[mf][q] = 0.f;

    // per-lane A row pointers per dt (step-invariant; OOB rows -> zpage)
    const float* pdt[3];
    #pragma unroll
    for (int dt = 0; dt < 3; ++dt) {
        int t = u0 + wu * 32 + lj - dt;
        pdt[dt] = (t >= 0 && t < T) ? (A + (size_t)(b * T + t) * K) : zpage;
    }

    auto issue_W = [&](unsigned short* dst, int ksg) {
        const unsigned short* sb = Wg + (size_t)ksg * WSTEP;
        #pragma unroll
        for (int p = 0; p < 7; ++p) {
            int P = p * 256 + tid;
            if (P < WJ * 4) {                          // wave-uniform
                __builtin_amdgcn_global_load_lds(
                    (const __attribute__((address_space(1))) void*)(sb + (size_t)P * 8),
                    (__attribute__((address_space(3))) void*)(dst + (p * 256 + w * 64) * 8),
                    16, 0, 0);
            }
        }
    };

    // absolute k offset for step s (tail kh1 remaps to 394: in-bounds, W-matched)
    auto aofs = [&](int s) -> int {
        return (s == 12 && kh == 1) ? 394 : s * 32 + kh * 16 + lh * 8;
    };
    auto loadA = [&](int s, float2* d) {
        int o = aofs(s);
        #pragma unroll
        for (int dt = 0; dt < 3; ++dt) {
            const float* p = pdt[dt] + o;
            #pragma unroll
            for (int q = 0; q < 4; ++q)
                d[dt * 4 + q] = *reinterpret_cast<const float2*>(p + 2 * q);
        }
    };

    float2 a2c[12], a2n[12];

    // prologue
    loadA(0, a2c);
    issue_W(&Ws[0], 0);
    __syncthreads();

    const int spl = (kh * 2 + lh) ^ (lj & 3);          // physical slot (swizzled)

    for (int s = 0; s < NSTEP; ++s) {
        const unsigned short* Wb = &Ws[(s & 1) * WSTEP];
        if (s + 1 < NSTEP) {
            issue_W(&Ws[((s + 1) & 1) * WSTEP], s + 1);
            loadA(s + 1, a2n);
        }
        // convert current A regs to bf16 frags
        bf16x8 af[3];
        #pragma unroll
        for (int dt = 0; dt < 3; ++dt) {
            union { bf16x8 v; __hip_bfloat162 h[4]; } u;
            #pragma unroll
            for (int q = 0; q < 4; ++q)
                u.h[q] = __float22bfloat162_rn(
                    make_float2(a2c[dt * 4 + q].x, a2c[dt * 4 + q].y));
            af[dt] = u.v;
        }
        // B reads + MFMA: dt0/dt1: 5 m-frags; dt2: 3 (j >= 416 invalid)
        #pragma unroll
        for (int dt = 0; dt < 3; ++dt) {
            const int nmf = (dt < 2) ? 5 : 3;
            #pragma unroll
            for (int mf = 0; mf < 5; ++mf) {
                if (mf < nmf) {
                    int j = dt * 160 + mf * 32 + lj;
                    bf16x8 bf = *reinterpret_cast<const bf16x8*>(&Wb[j * 32 + spl * 8]);
                    acc[mf] = __builtin_amdgcn_mfma_f32_32x32x16_bf16(
                        af[dt], bf, acc[mf], 0, 0, 0);
                }
            }
        }
        __syncthreads();
        if (s + 1 < NSTEP) {
            #pragma unroll
            for (int i = 0; i < 12; ++i) a2c[i] = a2n[i];
        }
    }

    // ---- kh reduction via LDS (reuse Ws) + normalized stores ----
    float* xch = reinterpret_cast<float*>(Ws);
    if (kh == 1) {
        #pragma unroll
        for (int mf = 0; mf < 5; ++mf) {
            int base = ((wu * 5 + mf) * 64 + lane) * 16;
            #pragma unroll
            for (int q = 0; q < 4; ++q)
                *reinterpret_cast<float4*>(&xch[base + q * 4]) =
                    make_float4(acc[mf][q * 4], acc[mf][q * 4 + 1],
                                acc[mf][q * 4 + 2], acc[mf][q * 4 + 3]);
        }
    }
    __syncthreads();
    if (kh == 0) {
        #pragma unroll
        for (int mf = 0; mf < 5; ++mf) {
            int base = ((wu * 5 + mf) * 64 + lane) * 16;
            float part[16];
            #pragma unroll
            for (int q = 0; q < 4; ++q) {
                float4 v = *reinterpret_cast<const float4*>(&xch[base + q * 4]);
                part[q * 4] = v.x; part[q * 4 + 1] = v.y;
                part[q * 4 + 2] = v.z; part[q * 4 + 3] = v.w;
            }
            int m = mf * 32 + lj;
            #pragma unroll
            for (int rg = 0; rg < 16; ++rg) {
                int u  = u0 + wu * 32 + (rg & 3) + 8 * (rg >> 2) + 4 * lh;
                int pe = u * HOP + m;
                int po = pe - (NFFT / 2);
                if (po >= 0 && po < OUTLEN)
                    out[(size_t)b * OUTLEN + po] = (acc[mf][rg] + part[rg]) * rssw[pe];
            }
        }
    }
}

// ---------------- launcher ----------------
extern "C" void kernel_launch(void* const* d_in, const int* in_sizes, int n_in,
                              void* d_out, int out_size, void* d_ws, size_t ws_size,
                              hipStream_t stream) {
    const float* x = (const float*)d_in[0];
    float* out = (float*)d_out;

    char* ws = (char*)d_ws;
    unsigned short* Wg = (unsigned short*)ws;                    // 346,112 B
    float* rssw = (float*)(ws + 346112);                         // 1,920,960 B
    float* zpage = (float*)(ws + 346112 + 1920960);              // 2048 B zeros

    hipMemsetAsync(zpage, 0, 2048, stream);
    {
        int total = NSTEP * WSTEP;
        build_wt<<<(total + 255) / 256, 256, 0, stream>>>(Wg);
    }
    {
        build_rssw<<<(ESTLEN + 255) / 256, 256, 0, stream>>>(rssw);
    }
    {
        dim3 grid((T + UT - 1) / UT, BB);                        // 47 x 16 = 752
        istft_fused<<<grid, 256, 0, stream>>>(x, Wg, rssw, zpage, out);
    }
}

// Round 6
// 71.827 us; speedup vs baseline: 1.3473x; 1.0738x over previous
//
#include <hip/hip_runtime.h>
#include <hip/hip_bf16.h>
#include <math.h>

// Problem constants (B=16, T=3000, F=201)
constexpr int BB     = 16;
constexpr int T      = 3000;
constexpr int F      = 201;
constexpr int NFFT   = 400;
constexpr int HOP    = 160;
constexpr int K      = 402;            // 2*F real/imag interleaved
constexpr int ESTLEN = (T - 1) * HOP + NFFT;   // 480240
constexpr int OUTLEN = ESTLEN - NFFT;          // 479840 per batch
constexpr float EPS  = 1e-12f;

constexpr int WJ    = 416;             // W rows per step (j 0..415; >=400 zero)
constexpr int WSTEP = WJ * 32;         // shorts per k32 table step = 13312 (26624 B)
constexpr int NSTEP = 13;              // k-steps of 32 (step 12 = tail 384..401)
constexpr int UT    = 96;              // u-rows per block (3 wu x 32)
constexpr int ARR   = 98;              // A rows per tile (halo 2)
constexpr int NTHR  = 384;             // 6 waves: (kh 0..1) x (wu 0..2)

typedef short bf16x8 __attribute__((ext_vector_type(8)));
typedef float f32x16 __attribute__((ext_vector_type(16)));

__device__ __forceinline__ unsigned short f2bf(float f) {
    unsigned int u = __float_as_uint(f);
    u = (u + 0x7fffu + ((u >> 16) & 1u)) >> 16;
    return (unsigned short)u;
}

// ---------------- table builders ----------------
// Baked bank-swizzle: Wg[ksg][j][op][i] = W[k = ksg*32 + (op ^ ((j>>1)&3))*8 + i][j]
// zero if j>=400 or k>=402.  (s8 = (j&1)*4 + (op^((j>>1)&3)) is bijective per 8 rows.)
__global__ void build_wt(unsigned short* __restrict__ Wg) {
    int idx = blockIdx.x * blockDim.x + threadIdx.x;
    if (idx >= NSTEP * WSTEP) return;
    int ksg = idx / WSTEP;
    int rem = idx - ksg * WSTEP;
    int j  = rem >> 5;
    int kk = rem & 31;
    int op = kk >> 3;
    int i  = kk & 7;
    int ol = op ^ ((j >> 1) & 3);
    int k  = ksg * 32 + ol * 8 + i;
    float v = 0.f;
    if (j < NFFT && k < K) {
        int f = k >> 1;
        bool is_re = (k & 1) == 0;
        float c = (f == 0 || f == F - 1) ? (1.f / 400.f) : (2.f / 400.f);
        int m = (j * f) % NFFT;
        float ang = (float)(2.0 * M_PI * (double)m / 400.0);
        float tw = is_re ? cosf(ang) : -sinf(ang);
        float win = 0.54f - 0.46f * cosf((float)(2.0 * M_PI * (double)j / 400.0));
        v = c * tw * win;
    }
    Wg[idx] = f2bf(v);
}

__global__ void build_rssw(float* __restrict__ rssw) {
    int p = blockIdx.x * blockDim.x + threadIdx.x;
    if (p >= ESTLEN) return;
    int t_hi = p / HOP; if (t_hi > T - 1) t_hi = T - 1;
    int t_lo = (p >= NFFT) ? ((p - NFFT) / HOP + 1) : 0;
    float s = 0.f;
    for (int t = t_lo; t <= t_hi; ++t) {
        int j = p - t * HOP;
        float w = 0.54f - 0.46f * cosf((float)(2.0 * M_PI * (double)j / 400.0));
        s += w * w;
    }
    rssw[p] = (s > EPS) ? 1.f / s : 1.f;
}

// ---------------- fused MFMA gather-GEMM ----------------
// Block 384 thr = 6 waves: (kh 0..1) x (wu 0..2). Tile 96u x 160m.
// Wave: 32u x 160m, k-half kh. 32x32x16 MFMA. K: 13 steps of 32 (step12 tail).
__global__ __launch_bounds__(NTHR, 3)
void istft_fused(const float* __restrict__ A, const unsigned short* __restrict__ Wg,
                 const float* __restrict__ rssw, const float* __restrict__ zpage,
                 float* __restrict__ out) {
    __shared__ __align__(16) unsigned short smem[2 * WSTEP + 2 * ARR * 32]; // 65792 B
    unsigned short* WsBuf = smem;
    unsigned short* AsBuf = smem + 2 * WSTEP;

    const int tid  = threadIdx.x;
    const int lane = tid & 63;
    const int w    = tid >> 6;
    const int kh   = (w >= 3) ? 1 : 0;
    const int wu   = kh ? (w - 3) : w;     // 0..2
    const int lj   = lane & 31;
    const int lh   = lane >> 5;
    const int b    = blockIdx.y;
    const int u0   = 1 + blockIdx.x * UT;
    const int tbase = u0 - 2;

    f32x16 acc[5];
    #pragma unroll
    for (int mf = 0; mf < 5; ++mf)
        #pragma unroll
        for (int q = 0; q < 16; ++q) acc[mf][q] = 0.f;

    // ---- A staging maps (coalesced: 4 threads/row x 32B; phys-linear LDS write,
    //      inverse-swizzled global source) ----
    const int r0  = tid >> 2, p0 = tid & 3;
    const int cl0 = p0 ^ ((r0 >> 1) & 3);
    const int t0  = tbase + r0;
    const float* arow0 = (t0 >= 0 && t0 < T) ? A + (size_t)(b * T + t0) * K : zpage;
    const bool has2 = (tid < 8);
    const int r1  = 96 + (tid >> 2), p1 = tid & 3;       // only tid<8 uses
    const int cl1 = p1 ^ ((r1 >> 1) & 3);
    const int t1  = tbase + r1;
    const float* arow1 = (t1 >= 0 && t1 < T) ? A + (size_t)(b * T + t1) * K : zpage;

    auto loadA = [&](int k0, bool tail, float4* d) {
        if (!tail) {
            const float* s0 = arow0 + k0 + cl0 * 8;
            d[0] = *reinterpret_cast<const float4*>(s0);
            d[1] = *reinterpret_cast<const float4*>(s0 + 4);
            if (has2) {
                const float* s1 = arow1 + k0 + cl1 * 8;
                d[2] = *reinterpret_cast<const float4*>(s1);
                d[3] = *reinterpret_cast<const float4*>(s1 + 4);
            }
        } else {
            float v0[8], v1[8];
            #pragma unroll
            for (int i = 0; i < 8; ++i) {
                int ka = k0 + cl0 * 8 + i;
                v0[i] = (ka < K) ? arow0[ka] : 0.f;
            }
            d[0] = make_float4(v0[0], v0[1], v0[2], v0[3]);
            d[1] = make_float4(v0[4], v0[5], v0[6], v0[7]);
            if (has2) {
                #pragma unroll
                for (int i = 0; i < 8; ++i) {
                    int ka = k0 + cl1 * 8 + i;
                    v1[i] = (ka < K) ? arow1[ka] : 0.f;
                }
                d[2] = make_float4(v1[0], v1[1], v1[2], v1[3]);
                d[3] = make_float4(v1[4], v1[5], v1[6], v1[7]);
            }
        }
    };

    auto writeA = [&](unsigned short* dst, const float4* d) {
        union { bf16x8 v; __hip_bfloat162 h[4]; } u;
        u.h[0] = __float22bfloat162_rn(make_float2(d[0].x, d[0].y));
        u.h[1] = __float22bfloat162_rn(make_float2(d[0].z, d[0].w));
        u.h[2] = __float22bfloat162_rn(make_float2(d[1].x, d[1].y));
        u.h[3] = __float22bfloat162_rn(make_float2(d[1].z, d[1].w));
        *reinterpret_cast<bf16x8*>(&dst[r0 * 32 + p0 * 8]) = u.v;
        if (has2) {
            union { bf16x8 v; __hip_bfloat162 h[4]; } u2;
            u2.h[0] = __float22bfloat162_rn(make_float2(d[2].x, d[2].y));
            u2.h[1] = __float22bfloat162_rn(make_float2(d[2].z, d[2].w));
            u2.h[2] = __float22bfloat162_rn(make_float2(d[3].x, d[3].y));
            u2.h[3] = __float22bfloat162_rn(make_float2(d[3].z, d[3].w));
            *reinterpret_cast<bf16x8*>(&dst[r1 * 32 + p1 * 8]) = u2.v;
        }
    };

    auto issueW = [&](unsigned short* dst, int ksg) {
        const unsigned short* sb = Wg + (size_t)ksg * WSTEP;
        #pragma unroll
        for (int p = 0; p < 5; ++p) {
            int P = p * NTHR + tid;
            if (P < WJ * 4) {                          // p=4: tid<128 -> waves 0,1 (uniform)
                __builtin_amdgcn_global_load_lds(
                    (const __attribute__((address_space(1))) void*)(sb + (size_t)P * 8),
                    (__attribute__((address_space(3))) void*)(dst + (p * NTHR + w * 64) * 8),
                    16, 0, 0);
            }
        }
    };

    const int q4  = kh * 2 + lh;                        // logical k-octet 0..3
    const int spl = q4 ^ ((lj >> 1) & 3);               // phys B slot (jbase % 8 == 0)

    auto compute = [&](int buf) {
        const unsigned short* Wb = WsBuf + buf * WSTEP;
        const unsigned short* Ab = AsBuf + buf * (ARR * 32);
        bf16x8 af[3];
        #pragma unroll
        for (int dt = 0; dt < 3; ++dt) {
            int r  = wu * 32 + lj + 2 - dt;
            int sl = q4 ^ ((r >> 1) & 3);
            af[dt] = *reinterpret_cast<const bf16x8*>(&Ab[r * 32 + sl * 8]);
        }
        #pragma unroll
        for (int dt = 0; dt < 3; ++dt) {
            const int nmf = (dt < 2) ? 5 : 3;           // dt2: j>=416 unused
            #pragma unroll
            for (int mf = 0; mf < 5; ++mf) {
                if (mf < nmf) {
                    int j = dt * 160 + mf * 32 + lj;
                    bf16x8 bf = *reinterpret_cast<const bf16x8*>(&Wb[j * 32 + spl * 8]);
                    acc[mf] = __builtin_amdgcn_mfma_f32_32x32x16_bf16(
                        af[dt], bf, acc[mf], 0, 0, 0);
                }
            }
        }
    };

    // ---- prologue: stage step 0 ----
    {
        float4 d[4];
        loadA(0, false, d);
        issueW(WsBuf, 0);
        writeA(AsBuf, d);
        __syncthreads();
    }

    // ---- main loop: issue(s+1) early -> compute(s) -> write A(s+1) late -> barrier ----
    for (int s = 0; s < NSTEP; ++s) {
        const int cur = s & 1, nxt = cur ^ 1;
        const bool dn = (s + 1 < NSTEP);
        float4 d[4];
        if (dn) {
            loadA((s + 1) * 32, (s + 1) == 12, d);
            issueW(WsBuf + nxt * WSTEP, s + 1);
        }
        compute(cur);
        if (dn) writeA(AsBuf + nxt * (ARR * 32), d);
        __syncthreads();
    }

    // ---- kh reduction via LDS + normalized stores ----
    float* xch = reinterpret_cast<float*>(smem);
    if (kh == 1) {
        #pragma unroll
        for (int mf = 0; mf < 5; ++mf) {
            int base = ((wu * 5 + mf) * 64 + lane) * 16;
            #pragma unroll
            for (int q = 0; q < 4; ++q)
                *reinterpret_cast<float4*>(&xch[base + q * 4]) =
                    make_float4(acc[mf][q * 4], acc[mf][q * 4 + 1],
                                acc[mf][q * 4 + 2], acc[mf][q * 4 + 3]);
        }
    }
    __syncthreads();
    if (kh == 0) {
        #pragma unroll
        for (int mf = 0; mf < 5; ++mf) {
            int base = ((wu * 5 + mf) * 64 + lane) * 16;
            float part[16];
            #pragma unroll
            for (int q = 0; q < 4; ++q) {
                float4 v = *reinterpret_cast<const float4*>(&xch[base + q * 4]);
                part[q * 4] = v.x; part[q * 4 + 1] = v.y;
                part[q * 4 + 2] = v.z; part[q * 4 + 3] = v.w;
            }
            int m = mf * 32 + lj;
            #pragma unroll
            for (int rg = 0; rg < 16; ++rg) {
                int u  = u0 + wu * 32 + (rg & 3) + 8 * (rg >> 2) + 4 * lh;
                int pe = u * HOP + m;
                int po = pe - (NFFT / 2);
                if (po >= 0 && po < OUTLEN)
                    out[(size_t)b * OUTLEN + po] = (acc[mf][rg] + part[rg]) * rssw[pe];
            }
        }
    }
}

// ---------------- launcher ----------------
extern "C" void kernel_launch(void* const* d_in, const int* in_sizes, int n_in,
                              void* d_out, int out_size, void* d_ws, size_t ws_size,
                              hipStream_t stream) {
    const float* x = (const float*)d_in[0];
    float* out = (float*)d_out;

    char* ws = (char*)d_ws;
    unsigned short* Wg = (unsigned short*)ws;                    // 346,112 B
    float* rssw = (float*)(ws + 346112);                         // 1,920,960 B
    float* zpage = (float*)(ws + 346112 + 1920960);              // 2048 B zeros

    hipMemsetAsync(zpage, 0, 2048, stream);
    {
        int total = NSTEP * WSTEP;
        build_wt<<<(total + 255) / 256, 256, 0, stream>>>(Wg);
    }
    {
        build_rssw<<<(ESTLEN + 255) / 256, 256, 0, stream>>>(rssw);
    }
    {
        dim3 grid((T + UT - 1) / UT, BB);                        // 32 x 16 = 512 = 2/CU
        istft_fused<<<grid, NTHR, 0, stream>>>(x, Wg, rssw, zpage, out);
    }
}